// Round 9
// baseline (1743.600 us; speedup 1.0000x reference)
//
#include <hip/hip_runtime.h>
#include <hip/hip_fp16.h>
#include <cstdint>

typedef _Float16 h2 __attribute__((ext_vector_type(2)));
typedef _Float16 h8 __attribute__((ext_vector_type(8)));
typedef float    f2 __attribute__((ext_vector_type(2)));
typedef float    f4 __attribute__((ext_vector_type(4)));
typedef uint32_t u4 __attribute__((ext_vector_type(4)));

#define BATCH 64
#define TSTEPS 1024
#define DDIM 512
#define HDIM 512

static __device__ __forceinline__ float fdot2(uint32_t w, uint32_t h, float acc) {
  return __builtin_amdgcn_fdot2(__builtin_bit_cast(h2, w), __builtin_bit_cast(h2, h), acc, false);
}

// Raw barrier: LDS-ordering only — NO vmcnt drain (xp loads / out stores stay
// in flight across barriers). Verified win in r4.
#define BAR_LDS()                                            \
  do {                                                       \
    __builtin_amdgcn_sched_barrier(0);                       \
    asm volatile("s_waitcnt lgkmcnt(0)" ::: "memory");       \
    __builtin_amdgcn_s_barrier();                            \
    __builtin_amdgcn_sched_barrier(0);                       \
  } while (0)

// ---------------------------------------------------------------------------
// prep: f16 weight conversion, pair-transposed Whh, bias sums.
// ---------------------------------------------------------------------------
__global__ void prep_kernel(const float* __restrict__ Wih_f, const float* __restrict__ Whh_f,
                            const float* __restrict__ bih_f, const float* __restrict__ bhh_f,
                            const float* __restrict__ Wih_b, const float* __restrict__ Whh_b,
                            const float* __restrict__ bih_b, const float* __restrict__ bhh_b,
                            _Float16* __restrict__ wi16, uint32_t* __restrict__ whT,
                            float* __restrict__ bsum) {
  int i = blockIdx.x * 256 + threadIdx.x;
  if (i < 2 * 512 * 512) {
    const float* s = (i < 512 * 512) ? Wih_f : Wih_b;
    wi16[i] = (_Float16)s[i & (512 * 512 - 1)];
  }
  if (i < 2 * 256 * 512) {
    int d = i >> 17; int rem = i & ((1 << 17) - 1);
    int kp = rem >> 9; int j = rem & 511;
    const float* W = d ? Whh_b : Whh_f;
    h2 p; p[0] = (_Float16)W[j * 512 + 2 * kp]; p[1] = (_Float16)W[j * 512 + 2 * kp + 1];
    whT[i] = __builtin_bit_cast(uint32_t, p);
  }
  if (i < 2 * 512) {
    int d = i >> 9, j = i & 511;
    bsum[i] = d ? (bih_b[j] + bhh_b[j]) : (bih_f[j] + bhh_f[j]);
  }
}

// ---------------------------------------------------------------------------
// xp_gemm (unchanged): xp[dir][m][n] f16, m = b*1024 + t (processing order).
// ---------------------------------------------------------------------------
__global__ __launch_bounds__(256) void xp_gemm(const float* __restrict__ x,
                                               const _Float16* __restrict__ wi,
                                               const float* __restrict__ bsum,
                                               _Float16* __restrict__ xp) {
  __shared__ _Float16 As[128][40];
  __shared__ _Float16 Bs[128][40];
  const int mt = blockIdx.x, nt = blockIdx.y, dir = blockIdx.z;
  const int m0 = mt * 128, n0 = nt * 128;
  const int tid = threadIdx.x;
  const int lane = tid & 63, w = tid >> 6;
  const int wr = w >> 1, wc = w & 1;
  const int ra = tid >> 1, hf = tid & 1;

  const int mrow = m0 + ra;
  const int bb = mrow >> 10, pp = mrow & 1023;
  const int srow = dir ? ((bb << 10) + (1023 - pp)) : mrow;
  const float*    xbase = x + (size_t)srow * 512 + hf * 16;
  const _Float16* wbase = wi + (size_t)dir * 512 * 512 + (size_t)(n0 + ra) * 512 + hf * 16;

  f4 acc[4][4];
  #pragma unroll
  for (int a = 0; a < 4; ++a)
    #pragma unroll
    for (int b = 0; b < 4; ++b) acc[a][b] = (f4)0.f;

  for (int k0 = 0; k0 < 512; k0 += 32) {
    f4 x0 = *(const f4*)(xbase + k0);
    f4 x1 = *(const f4*)(xbase + k0 + 4);
    f4 x2 = *(const f4*)(xbase + k0 + 8);
    f4 x3 = *(const f4*)(xbase + k0 + 12);
    h8 b0 = *(const h8*)(wbase + k0);
    h8 b1 = *(const h8*)(wbase + k0 + 8);
    h8 a0, a1;
    #pragma unroll
    for (int u = 0; u < 4; ++u) {
      a0[u] = (_Float16)x0[u]; a0[4 + u] = (_Float16)x1[u];
      a1[u] = (_Float16)x2[u]; a1[4 + u] = (_Float16)x3[u];
    }
    __syncthreads();
    *(h8*)&As[ra][hf * 16]     = a0;
    *(h8*)&As[ra][hf * 16 + 8] = a1;
    *(h8*)&Bs[ra][hf * 16]     = b0;
    *(h8*)&Bs[ra][hf * 16 + 8] = b1;
    __syncthreads();
    h8 af[4], bf[4];
    #pragma unroll
    for (int fm = 0; fm < 4; ++fm)
      af[fm] = *(const h8*)&As[wr * 64 + fm * 16 + (lane & 15)][(lane >> 4) * 8];
    #pragma unroll
    for (int fn = 0; fn < 4; ++fn)
      bf[fn] = *(const h8*)&Bs[wc * 64 + fn * 16 + (lane & 15)][(lane >> 4) * 8];
    #pragma unroll
    for (int fm = 0; fm < 4; ++fm)
      #pragma unroll
      for (int fn = 0; fn < 4; ++fn)
        acc[fm][fn] = __builtin_amdgcn_mfma_f32_16x16x32_f16(af[fm], bf[fn], acc[fm][fn], 0, 0, 0);
  }

  float bsv[4];
  #pragma unroll
  for (int fn = 0; fn < 4; ++fn)
    bsv[fn] = bsum[dir * 512 + n0 + wc * 64 + fn * 16 + (lane & 15)];
  #pragma unroll
  for (int fm = 0; fm < 4; ++fm)
    #pragma unroll
    for (int fn = 0; fn < 4; ++fn)
      #pragma unroll
      for (int u = 0; u < 4; ++u) {
        int m = m0 + wr * 64 + fm * 16 + (lane >> 4) * 4 + u;
        int n = n0 + wc * 64 + fn * 16 + (lane & 15);
        xp[((size_t)dir << 25) + (size_t)m * 512 + n] = (_Float16)(acc[fm][fn][u] + bsv[fn]);
      }
}

// ---------------------------------------------------------------------------
// rnn_rec (r9): in-wave k-reduction, ONE barrier/step, no psum epilogue.
//   512 threads, 8 waves. wave wj owns j in [wj*64, wj*64+64).
//   lane lv: kq = lv>>4 (k-quarter: pairs kq*64..kq*64+63), jj = lv&15;
//   j-quad = wj*64 + jj*4 + {0..3}.
//   Weights/lane: 64 pairs x 4 j = 256 u32 -> 52 pairs (208 u32) in regs,
//   12 pairs (48 u32) in LDS group-contiguous (12x b128, conflict-free).
//   h: FOUR bank-shifted copies (stride 1040 B; read addr = 1296*kq + 16*cb,
//   16B-aligned, banks 4kq+4cb+[0..3] disjoint across kq -> conflict-free
//   4-address broadcast b128), DOUBLE-buffered by parity (read t&1, write
//   (t+1)&1) so a single barrier orders write(t)->read(t+1) and buffers
//   remove the read(t)/write(t) WAR hazard.
//   k-reduce: acc += shfl_xor(acc,16); acc += shfl_xor(acc,32) — all lanes
//   end with full sums; tanh on all 8 waves (kq-redundant); kq==0 lanes
//   store out (16 lanes x 16 B = 256 B contiguous); every lane writes its
//   copy's h-pair (one b64).
// ---------------------------------------------------------------------------
__global__ __launch_bounds__(512, 2) void rnn_rec(const _Float16* __restrict__ xp,
                                                  const uint32_t* __restrict__ whT,
                                                  float* __restrict__ out) {
  extern __shared__ char smem[];
  uint32_t* wl = (uint32_t*)smem;          // 96 KB weights (group-contiguous)
  char* hbase  = smem + 98304;             // 2 parity bufs x 4 copies x 1040 B

  const int bid = blockIdx.x;
  const int dir = bid & 1, b = bid >> 1;
  const int l = threadIdx.x;
  const int wj = l >> 6, lv = l & 63;
  const int kq = lv >> 4, jj = lv & 15;
  const int jq0 = wj * 64 + jj * 4;

  // ---- weights: pair P = kq*64+p, 4 consecutive j (u4) ----
  const uint32_t* wb = whT + dir * (256 * 512) + (kq * 64) * 512 + jq0;
  u4 wq[52];
  #pragma unroll
  for (int p = 0; p < 52; ++p) wq[p] = *(const u4*)(wb + p * 512);

  // LDS pairs 52..63: group-contiguous, 8-lane groups own 1536 B
  char* wlb = (char*)wl + (l >> 3) * 1536 + (l & 7) * 16;
  #pragma unroll
  for (int g = 0; g < 12; ++g)
    *(u4*)(wlb + g * 128) = *(const u4*)(wb + (52 + g) * 512);

  // zero both h parity buffers (2 x 4160 B = 2080 dwords)
  {
    uint32_t* hz = (uint32_t*)hbase;
    for (int i = l; i < 2080; i += 512) hz[i] = 0;
  }
  __syncthreads();

  const _Float16* xpp = xp + ((size_t)dir << 25) + ((size_t)b << 19);
  float* op = out + (((size_t)(b * 2 + dir)) << 19);

  // per-lane h addresses (byte):
  //   read : parity*4160 + copy kq*1040 + slice kq*256 (+16*cb)
  //   write: parity*4160 + copy kq*1040 + pair (wj*32+2jj)*4
  const int hrd_off = kq * 1296;
  const int hwr_off = kq * 1040 + wj * 128 + jj * 8;

  for (int t = 0; t < TSTEPS; ++t) {
    // xp prefetch (4 f16 for this lane's j-quad); kq-redundant, L1-served.
    uint2 xv = *(const uint2*)(xpp + (size_t)t * 512 + jq0);

    const char* hrd = hbase + (t & 1) * 4160 + hrd_off;
    f4 acc = (f4)0.f;

    // pairs 0..51 (registers)
    #pragma unroll
    for (int cb = 0; cb < 13; ++cb) {
      u4 hv = *(const u4*)(hrd + cb * 16);         // 4-addr broadcast b128
      #pragma unroll
      for (int i = 0; i < 4; ++i) {
        const int p = cb * 4 + i;
        #pragma unroll
        for (int jn = 0; jn < 4; ++jn) acc[jn] = fdot2(wq[p][jn], hv[i], acc[jn]);
      }
    }
    // pairs 52..63 (LDS)
    #pragma unroll
    for (int cb2 = 0; cb2 < 3; ++cb2) {
      u4 hv = *(const u4*)(hrd + (13 + cb2) * 16);
      #pragma unroll
      for (int i = 0; i < 4; ++i) {
        u4 wv = *(const u4*)(wlb + (cb2 * 4 + i) * 128);   // conflict-free
        #pragma unroll
        for (int jn = 0; jn < 4; ++jn) acc[jn] = fdot2(wv[jn], hv[i], acc[jn]);
      }
    }

    // in-wave k-reduction: sum the 4 k-quarters (lanes lv, lv^16, lv^32, lv^48)
    #pragma unroll
    for (int jn = 0; jn < 4; ++jn) acc[jn] += __shfl_xor(acc[jn], 16, 64);
    #pragma unroll
    for (int jn = 0; jn < 4; ++jn) acc[jn] += __shfl_xor(acc[jn], 32, 64);

    // tanh epilogue: all lanes (kq-redundant), no extra barrier phase
    h2 x01 = __builtin_bit_cast(h2, xv.x);
    h2 x23 = __builtin_bit_cast(h2, xv.y);
    float s0 = acc[0] + (float)x01[0];
    float s1 = acc[1] + (float)x01[1];
    float s2 = acc[2] + (float)x23[0];
    float s3 = acc[3] + (float)x23[1];
    float h0 = 1.f - 2.f * __builtin_amdgcn_rcpf(__expf(2.f * s0) + 1.f);
    float h1 = 1.f - 2.f * __builtin_amdgcn_rcpf(__expf(2.f * s1) + 1.f);
    float h2v = 1.f - 2.f * __builtin_amdgcn_rcpf(__expf(2.f * s2) + 1.f);
    float h3 = 1.f - 2.f * __builtin_amdgcn_rcpf(__expf(2.f * s3) + 1.f);

    if (kq == 0) {
      f4 o; o[0] = h0; o[1] = h1; o[2] = h2v; o[3] = h3;
      *(f4*)(op + (size_t)t * 512 + jq0) = o;      // 256 B contiguous / 16 lanes
    }

    // h write: one b64 (pairs p0, p0+1) into the OTHER parity buffer, copy kq
    h2 pk0; pk0[0] = (_Float16)h0; pk0[1] = (_Float16)h1;
    h2 pk1; pk1[0] = (_Float16)h2v; pk1[1] = (_Float16)h3;
    uint2 hw;
    hw.x = __builtin_bit_cast(uint32_t, pk0);
    hw.y = __builtin_bit_cast(uint32_t, pk1);
    *(uint2*)(hbase + ((t + 1) & 1) * 4160 + hwr_off) = hw;

    BAR_LDS();                                      // single barrier per step
  }
}

// ---------------------------------------------------------------------------
extern "C" void kernel_launch(void* const* d_in, const int* in_sizes, int n_in,
                              void* d_out, int out_size, void* d_ws, size_t ws_size,
                              hipStream_t stream) {
  const float* x     = (const float*)d_in[0];
  const float* Wih_f = (const float*)d_in[1];
  const float* Whh_f = (const float*)d_in[2];
  const float* bih_f = (const float*)d_in[3];
  const float* bhh_f = (const float*)d_in[4];
  const float* Wih_b = (const float*)d_in[5];
  const float* Whh_b = (const float*)d_in[6];
  const float* bih_b = (const float*)d_in[7];
  const float* bhh_b = (const float*)d_in[8];

  char* ws = (char*)d_ws;
  _Float16* xp16 = (_Float16*)ws;                 // 128 MB
  _Float16* wi16 = (_Float16*)(ws + 134217728);   // 1 MB
  uint32_t* whT  = (uint32_t*)(ws + 135266304);   // 1 MB
  float*    bsum = (float*)(ws + 136314880);      // 4 KB
  float* out = (float*)d_out;

  prep_kernel<<<2048, 256, 0, stream>>>(Wih_f, Whh_f, bih_f, bhh_f,
                                        Wih_b, Whh_b, bih_b, bhh_b, wi16, whT, bsum);
  dim3 g(512, 4, 2);
  xp_gemm<<<g, 256, 0, stream>>>(x, wi16, bsum, xp16);

  const int REC_LDS = 106624;  // 96K wl + 2 x 4160 B h (4 bank-shifted copies)
  hipFuncSetAttribute((const void*)rnn_rec, hipFuncAttributeMaxDynamicSharedMemorySize, REC_LDS);
  rnn_rec<<<128, 512, REC_LDS, stream>>>(xp16, whT, out);
}